// Round 1
// baseline (969.191 us; speedup 1.0000x reference)
//
#include <hip/hip_runtime.h>

// Bahdanau attention, fp32: B=65536, W=20, E=128.
// One wave per batch row; lane owns elements {2*lane, 2*lane+1} (float2).
// value[b] cached in 40 VGPRs -> read HBM exactly once (671 MB floor).

#define NB 65536
#define NW 20
#define NE 128

__device__ __forceinline__ float fast_tanh(float x) {
    // tanh(x) = 1 - 2/(1 + e^{2x}); exp2-based, saturates correctly at +/-inf.
    float e = __builtin_amdgcn_exp2f(x * 2.885390081777927f);   // 2*log2(e)
    return 1.0f - 2.0f * __builtin_amdgcn_rcpf(1.0f + e);
}

__global__ void bahdanau_kernel(const float* __restrict__ query,
                                const float* __restrict__ value,
                                const float* __restrict__ W1,
                                const float* __restrict__ W2,
                                const float* __restrict__ W3,
                                float* __restrict__ out) {
    // LDS: W2/W3 interleaved {w2.x, w2.y, w3.x, w3.y} per (w, lane) -> one ds_read_b128,
    // 2-way bank aliasing only (free on gfx950). W1 as float pairs.
    __shared__ __align__(16) float4 lw23[NW * 64];
    __shared__ __align__(16) float  lw1[NE];

    for (int i = threadIdx.x; i < NE; i += blockDim.x) lw1[i] = W1[i];
    for (int i = threadIdx.x; i < NW * 64; i += blockDim.x) {
        int w = i >> 6, l = i & 63;
        float4 v;
        v.x = W2[w * NE + 2 * l];
        v.y = W2[w * NE + 2 * l + 1];
        v.z = W3[w * NE + 2 * l];
        v.w = W3[w * NE + 2 * l + 1];
        lw23[i] = v;
    }
    __syncthreads();

    const int lane          = threadIdx.x & 63;
    const int wave          = threadIdx.x >> 6;
    const int wavesPerBlock = blockDim.x >> 6;
    const int gw            = blockIdx.x * wavesPerBlock + wave;
    const int tw            = gridDim.x * wavesPerBlock;
    const int e0            = lane * 2;

    const float2 w1 = *(const float2*)(lw1 + e0);

    for (int b = gw; b < NB; b += tw) {
        const float2 q = *(const float2*)(query + (size_t)b * NE + e0);
        const float rq0 = q.x * w1.x;
        const float rq1 = q.y * w1.y;

        // Stage all 20 value rows for this b into registers (issues 20
        // independent global_load_dwordx2 up front -> latency overlap).
        float2 v[NW];
#pragma unroll
        for (int w = 0; w < NW; ++w)
            v[w] = *(const float2*)(value + ((size_t)b * NW + w) * NE + e0);

        float sc[NW];
#pragma unroll
        for (int w = 0; w < NW; ++w) {
            float4 w23 = lw23[w * 64 + lane];
            float t0 = fast_tanh(rq0 * v[w].x * w23.x);
            float t1 = fast_tanh(rq1 * v[w].y * w23.y);
            float p  = fmaf(t0, w23.z, t1 * w23.w);
            // butterfly reduce over 64 lanes -> sum replicated in every lane
#pragma unroll
            for (int off = 32; off; off >>= 1) p += __shfl_xor(p, off, 64);
            sc[w] = p;
        }

        // Redundant per-lane softmax over the 20 scores (all lanes identical).
        float m = sc[0];
#pragma unroll
        for (int w = 1; w < NW; ++w) m = fmaxf(m, sc[w]);
        float ssum = 0.f;
#pragma unroll
        for (int w = 0; w < NW; ++w) {
            sc[w] = __builtin_amdgcn_exp2f((sc[w] - m) * 1.4426950408889634f);
            ssum += sc[w];
        }
        const float inv = __builtin_amdgcn_rcpf(ssum);

        // context = sum_w a[w] * value[b][w][:] from register-cached value.
        float c0 = 0.f, c1 = 0.f;
#pragma unroll
        for (int w = 0; w < NW; ++w) {
            const float a = sc[w] * inv;
            c0 = fmaf(a, v[w].x, c0);
            c1 = fmaf(a, v[w].y, c1);
        }
        float2 o; o.x = c0; o.y = c1;
        *(float2*)(out + (size_t)b * NE + e0) = o;
    }
}

extern "C" void kernel_launch(void* const* d_in, const int* in_sizes, int n_in,
                              void* d_out, int out_size, void* d_ws, size_t ws_size,
                              hipStream_t stream) {
    const float* query = (const float*)d_in[0];
    const float* value = (const float*)d_in[1];
    const float* W1    = (const float*)d_in[2];
    const float* W2    = (const float*)d_in[3];
    const float* W3    = (const float*)d_in[4];
    float* out = (float*)d_out;

    dim3 grid(4096), block(256);
    hipLaunchKernelGGL(bahdanau_kernel, grid, block, 0, stream,
                       query, value, W1, W2, W3, out);
}

// Round 2
// 887.746 us; speedup vs baseline: 1.0917x; 1.0917x over previous
//
#include <hip/hip_runtime.h>
#include <math.h>

// Bahdanau attention, fp32: B=65536, W=20, E=128.
// v2: 16 lanes per b (lane owns 8 elems), 4 b per wave, online softmax.
// value read from HBM exactly once (671 MB); no big register arrays.

#define NB 65536
#define NW 20
#define NE 128
#define LOG2E 1.4426950408889634f

__device__ __forceinline__ float fast_tanh(float x) {
    // tanh(x) = 1 - 2/(1 + e^{2x}); exp2-based, saturates at +/-inf.
    float e = __builtin_amdgcn_exp2f(x * 2.885390081777927f);   // 2*log2(e)
    return 1.0f - 2.0f * __builtin_amdgcn_rcpf(1.0f + e);
}

__global__ __launch_bounds__(256)
void bahdanau_kernel(const float* __restrict__ query,
                     const float* __restrict__ value,
                     const float* __restrict__ W1,
                     const float* __restrict__ W2,
                     const float* __restrict__ W3,
                     float* __restrict__ out) {
    // W2/W3 staged to LDS as float4 (10 KB each). Natural row-major layout;
    // per (w, lane16) read = 2x ds_read_b128; groups 1-3 hit identical
    // addresses as group 0 -> broadcast, conflict-free.
    __shared__ __align__(16) float4 lw2[NW * NE / 4];   // 640
    __shared__ __align__(16) float4 lw3[NW * NE / 4];

    const float4* W2v = (const float4*)W2;
    const float4* W3v = (const float4*)W3;
    for (int i = threadIdx.x; i < NW * NE / 4; i += 256) {
        lw2[i] = W2v[i];
        lw3[i] = W3v[i];
    }
    __syncthreads();

    const int lane = threadIdx.x & 63;
    const int wave = threadIdx.x >> 6;
    const int grp  = lane >> 4;        // which of 4 b's in this wave
    const int l16  = lane & 15;        // lane within the 16-lane group
    const int b    = blockIdx.x * 16 + wave * 4 + grp;
    const int e0   = l16 * 8;          // this lane's 8 elements

    // rq = query[b] * W1 (kept in regs for the whole loop)
    const float* qp = query + (size_t)b * NE + e0;
    float4 qa = *(const float4*)(qp);
    float4 qb = *(const float4*)(qp + 4);
    float4 w1a = *(const float4*)(W1 + e0);
    float4 w1b = *(const float4*)(W1 + e0 + 4);
    float4 rqa, rqb;
    rqa.x = qa.x * w1a.x; rqa.y = qa.y * w1a.y; rqa.z = qa.z * w1a.z; rqa.w = qa.w * w1a.w;
    rqb.x = qb.x * w1b.x; rqb.y = qb.y * w1b.y; rqb.z = qb.z * w1b.z; rqb.w = qb.w * w1b.w;

    // online softmax state
    float m = -INFINITY, s = 0.f;
    float4 ca = {0.f, 0.f, 0.f, 0.f};
    float4 cb = {0.f, 0.f, 0.f, 0.f};

    const float* vp = value + (size_t)b * NW * NE + e0;
    const int wbase = l16 * 2;

#pragma unroll
    for (int w = 0; w < NW; ++w) {
        float4 va = *(const float4*)(vp + w * NE);
        float4 vb = *(const float4*)(vp + w * NE + 4);
        float4 w2a = lw2[w * 32 + wbase];
        float4 w2b = lw2[w * 32 + wbase + 1];
        float4 w3a = lw3[w * 32 + wbase];
        float4 w3b = lw3[w * 32 + wbase + 1];

        // partial score over this lane's 8 elements:
        // sum_e tanh(rq[e] * v[e] * W2[w][e]) * W3[w][e]
        float p;
        p = fast_tanh(rqa.x * va.x * w2a.x) * w3a.x;
        p = fmaf(fast_tanh(rqa.y * va.y * w2a.y), w3a.y, p);
        p = fmaf(fast_tanh(rqa.z * va.z * w2a.z), w3a.z, p);
        p = fmaf(fast_tanh(rqa.w * va.w * w2a.w), w3a.w, p);
        p = fmaf(fast_tanh(rqb.x * vb.x * w2b.x), w3b.x, p);
        p = fmaf(fast_tanh(rqb.y * vb.y * w2b.y), w3b.y, p);
        p = fmaf(fast_tanh(rqb.z * vb.z * w2b.z), w3b.z, p);
        p = fmaf(fast_tanh(rqb.w * vb.w * w2b.w), w3b.w, p);

        // reduce over the 16-lane group (offsets stay in-segment; cheap
        // DPP/ds_swizzle, one instr serves all 4 groups)
        p += __shfl_xor(p, 8, 16);
        p += __shfl_xor(p, 4, 16);
        p += __shfl_xor(p, 2, 16);
        p += __shfl_xor(p, 1, 16);

        // online softmax update; value consumed immediately (never re-read)
        float mnew  = fmaxf(m, p);
        float alpha = __builtin_amdgcn_exp2f((m - mnew) * LOG2E);
        float pw    = __builtin_amdgcn_exp2f((p - mnew) * LOG2E);
        s = fmaf(s, alpha, pw);
        ca.x = fmaf(ca.x, alpha, pw * va.x);
        ca.y = fmaf(ca.y, alpha, pw * va.y);
        ca.z = fmaf(ca.z, alpha, pw * va.z);
        ca.w = fmaf(ca.w, alpha, pw * va.w);
        cb.x = fmaf(cb.x, alpha, pw * vb.x);
        cb.y = fmaf(cb.y, alpha, pw * vb.y);
        cb.z = fmaf(cb.z, alpha, pw * vb.z);
        cb.w = fmaf(cb.w, alpha, pw * vb.w);
        m = mnew;
    }

    const float inv = __builtin_amdgcn_rcpf(s);
    float4 oa, ob;
    oa.x = ca.x * inv; oa.y = ca.y * inv; oa.z = ca.z * inv; oa.w = ca.w * inv;
    ob.x = cb.x * inv; ob.y = cb.y * inv; ob.z = cb.z * inv; ob.w = cb.w * inv;
    float* op = out + (size_t)b * NE + e0;
    *(float4*)(op)     = oa;
    *(float4*)(op + 4) = ob;
}

extern "C" void kernel_launch(void* const* d_in, const int* in_sizes, int n_in,
                              void* d_out, int out_size, void* d_ws, size_t ws_size,
                              hipStream_t stream) {
    const float* query = (const float*)d_in[0];
    const float* value = (const float*)d_in[1];
    const float* W1    = (const float*)d_in[2];
    const float* W2    = (const float*)d_in[3];
    const float* W3    = (const float*)d_in[4];
    float* out = (float*)d_out;

    // 16 b per block (4 waves x 4 groups) -> exactly 4096 blocks
    dim3 grid(NB / 16), block(256);
    hipLaunchKernelGGL(bahdanau_kernel, grid, block, 0, stream,
                       query, value, W1, W2, W3, out);
}